// Round 15
// baseline (218.158 us; speedup 1.0000x reference)
//
#include <hip/hip_runtime.h>

// MultiHeadAttention B=2,T=2048,D=1024,H=16,hd=64 fp32.
// R23: decisive A/B on gemm_qkv -- R18-flash's pairing lever (two 32-K
// sub-tiles per __syncthreads period, 16 periods instead of 32 barrier
// drains; 2 pair-buffers = 64KB LDS -> 2 blocks/CU, was 3). Trades block
// TLP (12->8 waves/CU) for halved barrier count; flash precedent (+7% at
// 2/CU) vs gemm history (TLP loss hurts). If this regresses, R22 is the
// documented floor of the 4-kernel structure.
// flash/gemm_out/split unchanged from R22.

typedef __attribute__((ext_vector_type(8))) short bf16x8;
typedef __attribute__((ext_vector_type(4))) float f32x4;
typedef __attribute__((ext_vector_type(4))) unsigned int u32x4;

#define E22 ((size_t)1 << 22)
#define E20 ((size_t)1 << 20)

__device__ __forceinline__ unsigned short f2bf(float x) {
    unsigned int u = __float_as_uint(x);
    u += 0x7fffu + ((u >> 16) & 1u);
    return (unsigned short)(u >> 16);
}
__device__ __forceinline__ unsigned int pk2bf(float a, float b) {
    // [b_hi16 | a_hi16] in one v_perm_b32
    return __builtin_amdgcn_perm(__float_as_uint(a), __float_as_uint(b), 0x03020706u);
}
__device__ __forceinline__ void gl16(const void* g, void* l) {
    __builtin_amdgcn_global_load_lds(
        (const __attribute__((address_space(1))) void*)g,
        (__attribute__((address_space(3))) void*)l, 16, 0, 0);
}
__device__ __forceinline__ f32x4 mfma16(bf16x8 a, bf16x8 b, f32x4 c) {
    return __builtin_amdgcn_mfma_f32_16x16x32_bf16(a, b, c, 0, 0, 0);
}

// ---------------------------------------------------------------------------
// split: fp32 -> bf16, 8 elems/thread. q/k/v -> [0,3*E22); Wq,Wk,Wv ->
// Wcat[3072,1024] at 3*E22; Wo -> 3*E22+3*E20. Grid 8192x256.
// ---------------------------------------------------------------------------
__global__ __launch_bounds__(256)
void split_all(const float* __restrict__ q, const float* __restrict__ k,
               const float* __restrict__ v, const float* __restrict__ wq,
               const float* __restrict__ wk, const float* __restrict__ wv,
               const float* __restrict__ wo, unsigned short* __restrict__ ws)
{
    const size_t t = (size_t)blockIdx.x * 256 + threadIdx.x;
    const size_t e = t * 8;
    const float* src; unsigned short* dst; size_t off;
    if (e < 3 * E22) {
        const unsigned int which = (unsigned int)(e >> 22);
        src = which == 0 ? q : (which == 1 ? k : v);
        off = e & (E22 - 1);
        dst = ws + (size_t)which * E22;
    } else {
        const size_t e2 = e - 3 * E22;
        const unsigned int which = (unsigned int)(e2 >> 20);
        off = e2 & (E20 - 1);
        src = which == 0 ? wq : (which == 1 ? wk : (which == 2 ? wv : wo));
        dst = ws + 3 * E22 + (size_t)which * E20;
    }
    const float4 xa = *(const float4*)(src + off);
    const float4 xb = *(const float4*)(src + off + 4);
    ushort4 ha, hb;
    ha.x = f2bf(xa.x); ha.y = f2bf(xa.y); ha.z = f2bf(xa.z); ha.w = f2bf(xa.w);
    hb.x = f2bf(xb.x); hb.y = f2bf(xb.y); hb.z = f2bf(xb.z); hb.w = f2bf(xb.w);
    *(ushort4*)(dst + off) = ha;
    *(ushort4*)(dst + off + 4) = hb;
}

// ---------------------------------------------------------------------------
// Fused QKV bf16 GEMM R23. Flat grid 768, XCD swizzle. Q output (which==0)
// PRE-SCALED by log2e/8. V output (which==2) key-PERMUTED within 32-groups
// (p = quad*8 + mt*4 + r, HW-verified). NEW: two 32-K sub-tiles per barrier
// period; 2 pair-buffers (4 sub-slots x (8KB X + 8KB W) = 64KB); stage pair
// p+1 after the period-p barrier (R18-flash schedule).
// ---------------------------------------------------------------------------
__global__ __launch_bounds__(256)
void gemm_qkv(const unsigned short* __restrict__ Xall,
              const unsigned short* __restrict__ Wcat,
              const float* __restrict__ bq, const float* __restrict__ bk,
              const float* __restrict__ bv, unsigned short* __restrict__ Qhp,
              unsigned short* __restrict__ Khp, unsigned short* __restrict__ Vtp)
{
    __shared__ unsigned short Xs[4 * 4096], Ws[4 * 4096];   // 4 sub-slots x 8KB
    const int tid = threadIdx.x;
    const int w = tid >> 6, ln = tid & 63;
    const int quad = ln >> 4, L = ln & 15;
    const int wy = w >> 1, wx = w & 1;

    const int bid = blockIdx.x;
    const int xcd = bid & 7, j = bid >> 3;
    const int gg = xcd * 12 + (j >> 3);
    const int which = gg >> 5, m_i = gg & 31, n_i = j & 7;
    const int m0 = m_i * 128;

    const unsigned short* X = Xall + (size_t)which * E22;
    const unsigned short* W = Wcat + ((size_t)which * 1024 + n_i * 128) * 1024;
    const float* bp = which == 0 ? bq : (which == 1 ? bk : bv);
    unsigned short* outp = which == 0 ? Qhp : (which == 1 ? Khp : Vtp);
    const float qscale = which == 0 ? 0.18033688011f : 1.0f;   // log2(e)/8

    // staging geometry (loop-invariant): 4 gl16 per wave per 32-K sub-tile
    const int ci0 = ln, ci1 = 64 + ln;
    const int row0 = w * 32 + (ci0 >> 2), row1 = w * 32 + (ci1 >> 2);
    const int gc0 = (ci0 & 3) ^ ((row0 >> 1) & 3);
    const int gc1 = (ci1 & 3) ^ ((row1 >> 1) & 3);
    const int lb0 = w * 2048, lb1 = w * 2048 + 1024;          // byte offsets
    const unsigned short* Xbp = X + (size_t)m0 * 1024;
    const size_t gx0 = (size_t)row0 * 1024 + gc0 * 8;
    const size_t gx1 = (size_t)row1 * 1024 + gc1 * 8;

    f32x4 acc[4][4];
#pragma unroll
    for (int i = 0; i < 4; ++i)
#pragma unroll
        for (int jj = 0; jj < 4; ++jj) { f32x4 z = {0.f,0.f,0.f,0.f}; acc[i][jj] = z; }

    // kt_ = 32-K sub-tile index (0..31), sb_ = sub-slot (0..3)
#define QSTAGE(kt_, sb_)                                                       \
    do {                                                                       \
        gl16(Xbp + gx0 + (kt_) * 32, (char*)Xs + (sb_) * 8192 + lb0);          \
        gl16(W   + gx0 + (kt_) * 32, (char*)Ws + (sb_) * 8192 + lb0);          \
        gl16(Xbp + gx1 + (kt_) * 32, (char*)Xs + (sb_) * 8192 + lb1);          \
        gl16(W   + gx1 + (kt_) * 32, (char*)Ws + (sb_) * 8192 + lb1);          \
    } while (0)

#define QCOMP(sb_)                                                             \
    do {                                                                       \
        const unsigned short* Xc = Xs + (sb_) * 4096;                          \
        const unsigned short* Wc = Ws + (sb_) * 4096;                          \
        bf16x8 ah[4], bh[4];                                                   \
        _Pragma("unroll")                                                      \
        for (int mt = 0; mt < 4; ++mt) {                                       \
            const int row = wy * 64 + mt * 16 + L;                             \
            ah[mt] = *(const bf16x8*)(Xc + row * 32 +                          \
                                      ((quad ^ ((row >> 1) & 3)) * 8));        \
        }                                                                      \
        _Pragma("unroll")                                                      \
        for (int nt = 0; nt < 4; ++nt) {                                       \
            const int row = wx * 64 + nt * 16 + L;                             \
            bh[nt] = *(const bf16x8*)(Wc + row * 32 +                          \
                                      ((quad ^ ((row >> 1) & 3)) * 8));        \
        }                                                                      \
        _Pragma("unroll")                                                      \
        for (int mt = 0; mt < 4; ++mt)                                         \
            _Pragma("unroll")                                                  \
            for (int nt = 0; nt < 4; ++nt)                                     \
                acc[mt][nt] = mfma16(ah[mt], bh[nt], acc[mt][nt]);             \
    } while (0)

    QSTAGE(0, 0);
    QSTAGE(1, 1);                              // pair 0 -> buffer 0 (slots 0,1)

    for (int p = 0; p < 16; ++p) {
        const int cur = p & 1;
        __syncthreads();                       // pair p staged & visible
        if (p < 15) {                          // stage pair p+1 -> other buffer
            QSTAGE(2 * p + 2, (cur ^ 1) * 2);
            QSTAGE(2 * p + 3, (cur ^ 1) * 2 + 1);
        }
        QCOMP(cur * 2);
        QCOMP(cur * 2 + 1);
    }
#undef QSTAGE
#undef QCOMP

#pragma unroll
    for (int mt = 0; mt < 4; ++mt)
#pragma unroll
        for (int nt = 0; nt < 4; ++nt) {
            const int gm0 = m0 + wy * 64 + mt * 16 + quad * 4;
            const int bn  = n_i * 128 + wx * 64 + nt * 16 + L;
            const float bvv = bp[bn];
            const int hh = bn >> 6, dd = bn & 63;
            if (which < 2) {
#pragma unroll
                for (int r = 0; r < 4; ++r) {
                    const int gm = gm0 + r;
                    const int bb = gm >> 11, tt = gm & 2047;
                    outp[((size_t)(bb * 16 + hh) * 2048 + tt) * 64 + dd] =
                        f2bf((acc[mt][nt][r] + bvv) * qscale);
                }
            } else {
                const int bb = gm0 >> 11, t0 = gm0 & 2047;
                // permuted key column: p0 = (t0&~31) | quad_k*8 | mt_k*4
                const int c5 = t0 & 31;
                const int p0 = (t0 & ~31) | (((c5 & 15) >> 2) << 3) | ((c5 >> 4) << 2);
                ushort4 pk;
                pk.x = f2bf(acc[mt][nt][0] + bvv);
                pk.y = f2bf(acc[mt][nt][1] + bvv);
                pk.z = f2bf(acc[mt][nt][2] + bvv);
                pk.w = f2bf(acc[mt][nt][3] + bvv);
                *(ushort4*)(outp + ((size_t)(bb * 16 + hh) * 64 + dd) * 2048 + p0) = pk;
            }
        }
}

// ---------------------------------------------------------------------------
// Wo GEMM R22 (unchanged). 128x64 tile, flat grid 512, XCD swizzle.
// 16 pair-periods; 3 pair-buffers (6 sub-bufs, 72KB). Depth-2 pair prefetch
// with counted vmcnt(6) + raw s_barrier.
// ---------------------------------------------------------------------------
__global__ __launch_bounds__(256)
void gemm_out(const unsigned short* __restrict__ X, const unsigned short* __restrict__ W,
              const float* __restrict__ bias, float* __restrict__ outp)
{
    __shared__ unsigned short Xs[6 * 4096], Ws[6 * 2048];   // 48KB + 24KB
    const int tid = threadIdx.x;
    const int w = tid >> 6, ln = tid & 63;
    const int quad = ln >> 4, L = ln & 15;

    const int bid = blockIdx.x;
    const int xcd = bid & 7, j = bid >> 3;
    const int m0 = (xcd * 4 + (j >> 4)) * 128;
    const int n0 = (j & 15) * 64;

    // staging geometry (loop-invariant): 3 gl16 per wave per 32-K sub-tile
    const int cix0 = ln, cix1 = 64 + ln;
    const int rowx0 = w * 32 + (cix0 >> 2), rowx1 = w * 32 + (cix1 >> 2);
    const int gcx0 = (cix0 & 3) ^ ((rowx0 >> 1) & 3);
    const int gcx1 = (cix1 & 3) ^ ((rowx1 >> 1) & 3);
    const int roww = w * 16 + (ln >> 2);
    const int gcw = (ln & 3) ^ ((roww >> 1) & 3);
    const size_t gxx0 = (size_t)(m0 + rowx0) * 1024 + gcx0 * 8;
    const size_t gxx1 = (size_t)(m0 + rowx1) * 1024 + gcx1 * 8;
    const size_t gww  = (size_t)(n0 + roww) * 1024 + gcw * 8;

    f32x4 acc[2][4];
#pragma unroll
    for (int i = 0; i < 2; ++i)
#pragma unroll
        for (int jj = 0; jj < 4; ++jj) { f32x4 z = {0.f,0.f,0.f,0.f}; acc[i][jj] = z; }

    // kt_ = 32-K sub-tile index (0..31); sb_ = sub-buffer slot (0..5)
#define OSTAGE(kt_, sb_)                                                       \
    do {                                                                       \
        gl16(X + gxx0 + (kt_) * 32, (char*)Xs + (sb_) * 8192 + w * 2048);      \
        gl16(X + gxx1 + (kt_) * 32, (char*)Xs + (sb_) * 8192 + w * 2048 + 1024); \
        gl16(W + gww  + (kt_) * 32, (char*)Ws + (sb_) * 4096 + w * 1024);      \
    } while (0)

#define OCOMP(sb_)                                                             \
    do {                                                                       \
        const unsigned short* Xc = Xs + (sb_) * 4096;                          \
        const unsigned short* Wc = Ws + (sb_) * 2048;                          \
        bf16x8 ah[2], bh[4];                                                   \
        _Pragma("unroll")                                                      \
        for (int mt = 0; mt < 2; ++mt) {                                       \
            const int row = w * 32 + mt * 16 + L;                              \
            ah[mt] = *(const bf16x8*)(Xc + row * 32 +                          \
                                      ((quad ^ ((row >> 1) & 3)) * 8));        \
        }                                                                      \
        _Pragma("unroll")                                                      \
        for (int nt = 0; nt < 4; ++nt) {                                       \
            const int row = nt * 16 + L;                                       \
            bh[nt] = *(const bf16x8*)(Wc + row * 32 +                          \
                                      ((quad ^ ((row >> 1) & 3)) * 8));        \
        }                                                                      \
        _Pragma("unroll")                                                      \
        for (int mt = 0; mt < 2; ++mt)                                         \
            _Pragma("unroll")                                                  \
            for (int nt = 0; nt < 4; ++nt)                                     \
                acc[mt][nt] = mfma16(ah[mt], bh[nt], acc[mt][nt]);             \
    } while (0)

    OSTAGE(0, 0); OSTAGE(1, 1);     // pair 0
    OSTAGE(2, 2); OSTAGE(3, 3);     // pair 1

    for (int p = 0; p < 16; ++p) {
        // own pair's 6 loads done; pair p+1's 6 may stay in flight
        if (p < 15) {
            asm volatile("s_waitcnt vmcnt(6)" ::: "memory");
        } else {
            asm volatile("s_waitcnt vmcnt(0)" ::: "memory");
        }
        __builtin_amdgcn_s_barrier();
        asm volatile("" ::: "memory");
        const int sb = (2 * p) % 6;
        if (p < 14) {               // stage pair p+2 into slot computed at p-1
            const int st = (2 * p + 4) % 6;
            OSTAGE(2 * p + 4, st);
            OSTAGE(2 * p + 5, st + 1);
        }
        OCOMP(sb);
        OCOMP(sb + 1);
    }
#undef OSTAGE
#undef OCOMP

#pragma unroll
    for (int mt = 0; mt < 2; ++mt)
#pragma unroll
        for (int nt = 0; nt < 4; ++nt) {
            const int gm0 = m0 + w * 32 + mt * 16 + quad * 4;
            const int gn  = n0 + nt * 16 + L;
            const float bvv = bias[gn];
#pragma unroll
            for (int r = 0; r < 4; ++r)
                outp[(size_t)(gm0 + r) * 1024 + gn] = acc[mt][nt][r] + bvv;
        }
}

// ---------------------------------------------------------------------------
// Flash R18 (unchanged). Flat grid 512 (256 thr): xcd=bid&7, j=bid>>3,
// bh=xcd*4+(j&3), qt=j>>2 (q-tile 128). Wave (wq,wk) owns q-half wq (64
// rows) x key-half wk (32 keys of each 64-key sub-tile). S^T = K Q^T, O^T =
// V^T P^T, P in registers (slot k = quad*8 + mt*4 + r). TWO 64-key sub-
// tiles per barrier period (16 periods); K/V double-buffered at period
// granularity. V LDS key-permuted (producer) -> av = one ds_read_b128/frag.
// LDS 66KB -> 2 blocks/CU. Epilogue O-reduce through retired LDS.
// ---------------------------------------------------------------------------
__global__ __launch_bounds__(256, 2)
void flash(const unsigned short* __restrict__ Qh, const unsigned short* __restrict__ Kh,
           const unsigned short* __restrict__ Vt, unsigned short* __restrict__ A)
{
    __shared__ unsigned short SM[32768];         // 64KB: K [0,32KB), V [32,64KB)
    __shared__ float Lsc[2 * 4 * 64];            // 2KB cross-wave lacc scalars
    const int tid = threadIdx.x;
    const int w = tid >> 6, ln = tid & 63;
    const int quad = ln >> 4, L = ln & 15;
    const int wq = w & 1, wk = w >> 1;

    const int bid = blockIdx.x;
    const int xcd = bid & 7, j = bid >> 3;
    const int bh_i = xcd * 4 + (j & 3);
    const int qt = j >> 2;                       // 0..15, 128-row q tiles
    const int b = bh_i >> 4, h = bh_i & 15;

    const unsigned short* Qb = Qh + ((size_t)bh_i * 2048 + qt * 128 + wq * 64) * 64;
    const unsigned short* Kb = Kh + (size_t)bh_i * 2048 * 64;
    const unsigned short* Vb = Vt + (size_t)bh_i * 64 * 2048;

    // Q as B-operand: B[n=q=nt*16+L][k=d]
    bf16x8 bq[4][2];
#pragma unroll
    for (int nt = 0; nt < 4; ++nt)
#pragma unroll
        for (int kc = 0; kc < 2; ++kc)
            bq[nt][kc] = *(const bf16x8*)(Qb + (nt * 16 + L) * 64 + kc * 32 + quad * 8);

    const short one_bf = (short)0x3F80;
    bf16x8 bone = {one_bf, one_bf, one_bf, one_bf, one_bf, one_bf, one_bf, one_bf};

    f32x4 o[4][4];        // O^T partial: [mtd over d][nt over q]
    f32x4 lacc[4];
#pragma unroll
    for (int mtd = 0; mtd < 4; ++mtd)
#pragma unroll
        for (int nt = 0; nt < 4; ++nt) { f32x4 z = {0.f,0.f,0.f,0.f}; o[mtd][nt] = z; }
#pragma unroll
    for (int nt = 0; nt < 4; ++nt) { f32x4 z = {0.f,0.f,0.f,0.f}; lacc[nt] = z; }

    // staging: per 64-key sub-tile, seg = w*2+i over 8 segs of 1KB
    const int ci0 = (w * 2 + 0) * 64 + ln, ci1 = (w * 2 + 1) * 64 + ln;
    const int rr0 = ci0 >> 3, rr1 = ci1 >> 3;
    const int gc0 = (ci0 & 7) ^ (rr0 & 7), gc1 = (ci1 & 7) ^ (rr1 & 7);

    // one sub-tile (global tile index kt_, period-buffer b_, sub-slot s_)
#define STAGE1(kt_, b_, s_)                                                     \
    do {                                                                        \
        gl16(Kb + (size_t)((kt_) * 64 + rr0) * 64 + gc0 * 8,                    \
             (char*)SM + (b_) * 16384 + (s_) * 8192 + (w * 2 + 0) * 1024);      \
        gl16(Kb + (size_t)((kt_) * 64 + rr1) * 64 + gc1 * 8,                    \
             (char*)SM + (b_) * 16384 + (s_) * 8192 + (w * 2 + 1) * 1024);      \
        gl16(Vb + (size_t)rr0 * 2048 + (kt_) * 64 + gc0 * 8,                    \
             (char*)SM + 32768 + (b_) * 16384 + (s_) * 8192 + (w * 2 + 0) * 1024); \
        gl16(Vb + (size_t)rr1 * 2048 + (kt_) * 64 + gc1 * 8,                    \
             (char*)SM + 32768 + (b_) * 16384 + (s_) * 8192 + (w * 2 + 1) * 1024); \
    } while (0)

    // compute one 64-key sub-tile from (buffer b_, sub-slot s_)
#define SUBCOMP(b_, s_)                                                         \
    do {                                                                        \
        const unsigned short* Ksb = SM + (b_) * 8192 + (s_) * 4096;             \
        const unsigned short* Vsb = SM + 16384 + (b_) * 8192 + (s_) * 4096;     \
        bf16x8 ak[2][2];                                                        \
        _Pragma("unroll")                                                       \
        for (int mt = 0; mt < 2; ++mt)                                          \
            _Pragma("unroll")                                                   \
            for (int kc = 0; kc < 2; ++kc) {                                    \
                const int row = wk * 32 + mt * 16 + L;                          \
                ak[mt][kc] = *(const bf16x8*)(Ksb + row * 64 +                  \
                                              (((kc * 4 + quad) ^ (L & 7)) * 8)); \
            }                                                                   \
        f32x4 s[2][4];                                                          \
        _Pragma("unroll")                                                       \
        for (int mt = 0; mt < 2; ++mt)                                          \
            _Pragma("unroll")                                                   \
            for (int nt = 0; nt < 4; ++nt) {                                    \
                f32x4 z = {0.f, 0.f, 0.f, 0.f};                                 \
                z = mfma16(ak[mt][0], bq[nt][0], z);                            \
                z = mfma16(ak[mt][1], bq[nt][1], z);                            \
                s[mt][nt] = z;                                                  \
            }                                                                   \
        bf16x8 pbx[4];                                                          \
        _Pragma("unroll")                                                       \
        for (int nt = 0; nt < 4; ++nt) {                                        \
            u32x4 pd;                                                           \
            pd.x = pk2bf(__builtin_amdgcn_exp2f(s[0][nt][0]),                   \
                         __builtin_amdgcn_exp2f(s[0][nt][1]));                  \
            pd.y = pk2bf(__builtin_amdgcn_exp2f(s[0][nt][2]),                   \
                         __builtin_amdgcn_exp2f(s[0][nt][3]));                  \
            pd.z = pk2bf(__builtin_amdgcn_exp2f(s[1][nt][0]),                   \
                         __builtin_amdgcn_exp2f(s[1][nt][1]));                  \
            pd.w = pk2bf(__builtin_amdgcn_exp2f(s[1][nt][2]),                   \
                         __builtin_amdgcn_exp2f(s[1][nt][3]));                  \
            pbx[nt] = __builtin_bit_cast(bf16x8, pd);                           \
        }                                                                       \
        bf16x8 av[4];                                                           \
        _Pragma("unroll")                                                       \
        for (int mtd = 0; mtd < 4; ++mtd) {                                     \
            const int row = mtd * 16 + L;                                       \
            av[mtd] = *(const bf16x8*)(Vsb + row * 64 +                         \
                                       (((wk * 4 + quad) ^ (L & 7)) * 8));      \
        }                                                                       \
        _Pragma("unroll")                                                       \
        for (int mtd = 0; mtd < 4; ++mtd)                                       \
            _Pragma("unroll")                                                   \
            for (int nt = 0; nt < 4; ++nt)                                      \
                o[mtd][nt] = mfma16(av[mtd], pbx[nt], o[mtd][nt]);              \
        _Pragma("unroll")                                                       \
        for (int nt = 0; nt < 4; ++nt)                                          \
            lacc[nt] = mfma16(bone, pbx[nt], lacc[nt]);                         \
    } while (0)

    STAGE1(0, 0, 0);
    STAGE1(1, 0, 1);

    for (int p = 0; p < 16; ++p) {
        const int cur = p & 1;
        __syncthreads();                       // period p staged & visible
        if (p < 15) {                          // prefetch period p+1
            STAGE1(2 * p + 2, cur ^ 1, 0);
            STAGE1(2 * p + 3, cur ^ 1, 1);
        }
        SUBCOMP(cur, 0);
        SUBCOMP(cur, 1);
    }
#undef STAGE1
#undef SUBCOMP

    // cross-wave reduction over key-halves through retired LDS
    __syncthreads();
    float* Rb = (float*)SM;               // 8192 floats = 32 KB (of 64)
    if (wk == 1) {
#pragma unroll
        for (int mtd = 0; mtd < 4; ++mtd)
#pragma unroll
            for (int nt = 0; nt < 4; ++nt)
                *(f32x4*)(Rb + wq * 4096 + (mtd * 4 + nt) * 256 + ln * 4) = o[mtd][nt];
#pragma unroll
        for (int nt = 0; nt < 4; ++nt)
            Lsc[wq * 256 + nt * 64 + ln] = lacc[nt][0];
    }
    __syncthreads();
    if (wk == 0) {
#pragma unroll
        for (int mtd = 0; mtd < 4; ++mtd)
#pragma unroll
            for (int nt = 0; nt < 4; ++nt)
                o[mtd][nt] += *(const f32x4*)(Rb + wq * 4096 + (mtd * 4 + nt) * 256 + ln * 4);

        // epilogue: O^T/l -> bf16 into A [B*T, D]; lane q=nt*16+L, rows d.
#pragma unroll
        for (int nt = 0; nt < 4; ++nt) {
            const float lsum = lacc[nt][0] + Lsc[wq * 256 + nt * 64 + ln];
            const float inv = 1.0f / lsum;
            const int qrow = b * 2048 + qt * 128 + wq * 64 + nt * 16 + L;
#pragma unroll
            for (int mtd = 0; mtd < 4; ++mtd) {
                const int d0 = mtd * 16 + quad * 4;
                ushort4 pk;
                pk.x = f2bf(o[mtd][nt][0] * inv);
                pk.y = f2bf(o[mtd][nt][1] * inv);
                pk.z = f2bf(o[mtd][nt][2] * inv);
                pk.w = f2bf(o[mtd][nt][3] * inv);
                *(ushort4*)(A + (size_t)qrow * 1024 + h * 64 + d0) = pk;
            }
        }
    }
}

// ---------------------------------------------------------------------------
extern "C" void kernel_launch(void* const* d_in, const int* in_sizes, int n_in,
                              void* d_out, int out_size, void* d_ws, size_t ws_size,
                              hipStream_t stream) {
    const float* q  = (const float*)d_in[0];
    const float* k  = (const float*)d_in[1];
    const float* v  = (const float*)d_in[2];
    const float* Wq = (const float*)d_in[3];
    const float* bq = (const float*)d_in[4];
    const float* Wk = (const float*)d_in[5];
    const float* bk = (const float*)d_in[6];
    const float* Wv = (const float*)d_in[7];
    const float* bv = (const float*)d_in[8];
    const float* Wo = (const float*)d_in[9];
    const float* bo = (const float*)d_in[10];

    unsigned short* W = (unsigned short*)d_ws;
    unsigned short *Xall = W;                      // q,k,v bf16 [3*E22]
    unsigned short *Wcat = W + 3 * E22;            // [3072,1024] bf16
    unsigned short *Wob  = Wcat + 3 * E20;         // [1024,1024] bf16
    unsigned short *Qhp  = W + 4 * E22;            // [B,H,T,64] (pre-scaled)
    unsigned short *Khp  = W + 5 * E22;
    unsigned short *Vtp  = W + 6 * E22;            // [B,H,64,T] key-permuted
    unsigned short *A    = W;                      // reuse q_b (dead)

    split_all<<<8192, 256, 0, stream>>>(q, k, v, Wq, Wk, Wv, Wo, W);

    gemm_qkv<<<768, 256, 0, stream>>>(Xall, Wcat, bq, bk, bv, Qhp, Khp, Vtp);

    flash<<<512, 256, 0, stream>>>(Qhp, Khp, Vtp, A);

    gemm_out<<<512, 256, 0, stream>>>(A, Wob, bo, (float*)d_out);
}

// Round 16
// 206.324 us; speedup vs baseline: 1.0574x; 1.0574x over previous
//
#include <hip/hip_runtime.h>

// MultiHeadAttention B=2,T=2048,D=1024,H=16,hd=64 fp32.
// R24 == R22 exact revert (session best, 208.7us). R23's gemm_qkv pairing
// (2 blocks/CU) regressed 42->57us -- TLP loss dominated barrier savings,
// closing the last open structural question. Design space now mapped:
//  - gemm_qkv: 128x128/4w/3-buf-vmcnt(4)/grid768 beats 8-wave(R19),
//    128x64-6blk(R20), paired-2blk(R23).
//  - flash: q128 + P-in-registers (slot relabel) + paired 128-key periods
//    beats q64(R10), 512-thr(R13), counted-vmcnt(R14), no-LDS(R15/R17).
//  - gemm_out: paired + depth-2 vmcnt(6) (best of its ladder).
//  - split: 8 elem/thread.

typedef __attribute__((ext_vector_type(8))) short bf16x8;
typedef __attribute__((ext_vector_type(4))) float f32x4;
typedef __attribute__((ext_vector_type(4))) unsigned int u32x4;

#define E22 ((size_t)1 << 22)
#define E20 ((size_t)1 << 20)

__device__ __forceinline__ unsigned short f2bf(float x) {
    unsigned int u = __float_as_uint(x);
    u += 0x7fffu + ((u >> 16) & 1u);
    return (unsigned short)(u >> 16);
}
__device__ __forceinline__ unsigned int pk2bf(float a, float b) {
    // [b_hi16 | a_hi16] in one v_perm_b32
    return __builtin_amdgcn_perm(__float_as_uint(a), __float_as_uint(b), 0x03020706u);
}
__device__ __forceinline__ void gl16(const void* g, void* l) {
    __builtin_amdgcn_global_load_lds(
        (const __attribute__((address_space(1))) void*)g,
        (__attribute__((address_space(3))) void*)l, 16, 0, 0);
}
__device__ __forceinline__ f32x4 mfma16(bf16x8 a, bf16x8 b, f32x4 c) {
    return __builtin_amdgcn_mfma_f32_16x16x32_bf16(a, b, c, 0, 0, 0);
}

// ---------------------------------------------------------------------------
// split: fp32 -> bf16, 8 elems/thread. q/k/v -> [0,3*E22); Wq,Wk,Wv ->
// Wcat[3072,1024] at 3*E22; Wo -> 3*E22+3*E20. Grid 8192x256.
// All segment boundaries are multiples of 8 -> no straddle.
// ---------------------------------------------------------------------------
__global__ __launch_bounds__(256)
void split_all(const float* __restrict__ q, const float* __restrict__ k,
               const float* __restrict__ v, const float* __restrict__ wq,
               const float* __restrict__ wk, const float* __restrict__ wv,
               const float* __restrict__ wo, unsigned short* __restrict__ ws)
{
    const size_t t = (size_t)blockIdx.x * 256 + threadIdx.x;
    const size_t e = t * 8;
    const float* src; unsigned short* dst; size_t off;
    if (e < 3 * E22) {
        const unsigned int which = (unsigned int)(e >> 22);
        src = which == 0 ? q : (which == 1 ? k : v);
        off = e & (E22 - 1);
        dst = ws + (size_t)which * E22;
    } else {
        const size_t e2 = e - 3 * E22;
        const unsigned int which = (unsigned int)(e2 >> 20);
        off = e2 & (E20 - 1);
        src = which == 0 ? wq : (which == 1 ? wk : (which == 2 ? wv : wo));
        dst = ws + 3 * E22 + (size_t)which * E20;
    }
    const float4 xa = *(const float4*)(src + off);
    const float4 xb = *(const float4*)(src + off + 4);
    ushort4 ha, hb;
    ha.x = f2bf(xa.x); ha.y = f2bf(xa.y); ha.z = f2bf(xa.z); ha.w = f2bf(xa.w);
    hb.x = f2bf(xb.x); hb.y = f2bf(xb.y); hb.z = f2bf(xb.z); hb.w = f2bf(xb.w);
    *(ushort4*)(dst + off) = ha;
    *(ushort4*)(dst + off + 4) = hb;
}

// ---------------------------------------------------------------------------
// Fused QKV bf16 GEMM (R18-exact). Flat grid 768, XCD swizzle. Q output
// (which==0) PRE-SCALED by log2e/8 so flash's softmax is a bare exp2.
// V output (which==2) stored with keys PERMUTED within each 32-key group
// (p = quad*8 + mt*4 + r for key = mt*16 + quad*4 + r) -- HW-verified --
// so flash's PV A-frag is one contiguous LDS granule.
// Pipeline: 3-buffer LDS, depth-2 prefetch, counted vmcnt(4) + raw s_barrier.
// ---------------------------------------------------------------------------
__global__ __launch_bounds__(256)
void gemm_qkv(const unsigned short* __restrict__ Xall,
              const unsigned short* __restrict__ Wcat,
              const float* __restrict__ bq, const float* __restrict__ bk,
              const float* __restrict__ bv, unsigned short* __restrict__ Qhp,
              unsigned short* __restrict__ Khp, unsigned short* __restrict__ Vtp)
{
    __shared__ unsigned short Xs[3 * 4096], Ws[3 * 4096];   // 3 bufs x 8KB each
    const int tid = threadIdx.x;
    const int w = tid >> 6, ln = tid & 63;
    const int quad = ln >> 4, L = ln & 15;
    const int wy = w >> 1, wx = w & 1;

    const int bid = blockIdx.x;
    const int xcd = bid & 7, j = bid >> 3;
    const int gg = xcd * 12 + (j >> 3);
    const int which = gg >> 5, m_i = gg & 31, n_i = j & 7;
    const int m0 = m_i * 128;

    const unsigned short* X = Xall + (size_t)which * E22;
    const unsigned short* W = Wcat + ((size_t)which * 1024 + n_i * 128) * 1024;
    const float* bp = which == 0 ? bq : (which == 1 ? bk : bv);
    unsigned short* outp = which == 0 ? Qhp : (which == 1 ? Khp : Vtp);
    const float qscale = which == 0 ? 0.18033688011f : 1.0f;   // log2(e)/8

    // staging geometry (loop-invariant): 4 gl16 per wave per K-tile
    const int ci0 = ln, ci1 = 64 + ln;
    const int row0 = w * 32 + (ci0 >> 2), row1 = w * 32 + (ci1 >> 2);
    const int gc0 = (ci0 & 3) ^ ((row0 >> 1) & 3);
    const int gc1 = (ci1 & 3) ^ ((row1 >> 1) & 3);
    const int lb0 = w * 2048, lb1 = w * 2048 + 1024;          // byte offsets
    const unsigned short* Xbp = X + (size_t)m0 * 1024;
    const size_t gx0 = (size_t)row0 * 1024 + gc0 * 8;
    const size_t gx1 = (size_t)row1 * 1024 + gc1 * 8;

    f32x4 acc[4][4];
#pragma unroll
    for (int i = 0; i < 4; ++i)
#pragma unroll
        for (int jj = 0; jj < 4; ++jj) { f32x4 z = {0.f,0.f,0.f,0.f}; acc[i][jj] = z; }

#define QSTAGE(k0_, bo_)                                                       \
    do {                                                                       \
        gl16(Xbp + gx0 + (k0_), (char*)Xs + (bo_) + lb0);                      \
        gl16(W   + gx0 + (k0_), (char*)Ws + (bo_) + lb0);                      \
        gl16(Xbp + gx1 + (k0_), (char*)Xs + (bo_) + lb1);                      \
        gl16(W   + gx1 + (k0_), (char*)Ws + (bo_) + lb1);                      \
    } while (0)

#define QCOMP(eo_)                                                             \
    do {                                                                       \
        const unsigned short* Xc = Xs + (eo_);                                 \
        const unsigned short* Wc = Ws + (eo_);                                 \
        bf16x8 ah[4], bh[4];                                                   \
        _Pragma("unroll")                                                      \
        for (int mt = 0; mt < 4; ++mt) {                                       \
            const int row = wy * 64 + mt * 16 + L;                             \
            ah[mt] = *(const bf16x8*)(Xc + row * 32 +                          \
                                      ((quad ^ ((row >> 1) & 3)) * 8));        \
        }                                                                      \
        _Pragma("unroll")                                                      \
        for (int nt = 0; nt < 4; ++nt) {                                       \
            const int row = wx * 64 + nt * 16 + L;                             \
            bh[nt] = *(const bf16x8*)(Wc + row * 32 +                          \
                                      ((quad ^ ((row >> 1) & 3)) * 8));        \
        }                                                                      \
        _Pragma("unroll")                                                      \
        for (int mt = 0; mt < 4; ++mt)                                         \
            _Pragma("unroll")                                                  \
            for (int nt = 0; nt < 4; ++nt)                                     \
                acc[mt][nt] = mfma16(ah[mt], bh[nt], acc[mt][nt]);             \
    } while (0)

    QSTAGE(0, 0);
    QSTAGE(32, 8192);

    int cur = 0;
    for (int kt = 0; kt < 31; ++kt) {
        // own 4 loads for buf[cur] done; next tile's 4 may stay in flight
        asm volatile("s_waitcnt vmcnt(4)" ::: "memory");
        __builtin_amdgcn_s_barrier();
        asm volatile("" ::: "memory");
        if (kt < 30) {
            int st = cur + 2; if (st >= 3) st -= 3;   // buf read in iter kt-1
            QSTAGE((kt + 2) * 32, st * 8192);
        }
        QCOMP(cur * 4096);
        cur = (cur == 2) ? 0 : cur + 1;
    }
    asm volatile("s_waitcnt vmcnt(0)" ::: "memory");
    __builtin_amdgcn_s_barrier();
    asm volatile("" ::: "memory");
    QCOMP(cur * 4096);
#undef QSTAGE
#undef QCOMP

#pragma unroll
    for (int mt = 0; mt < 4; ++mt)
#pragma unroll
        for (int nt = 0; nt < 4; ++nt) {
            const int gm0 = m0 + wy * 64 + mt * 16 + quad * 4;
            const int bn  = n_i * 128 + wx * 64 + nt * 16 + L;
            const float bvv = bp[bn];
            const int hh = bn >> 6, dd = bn & 63;
            if (which < 2) {
#pragma unroll
                for (int r = 0; r < 4; ++r) {
                    const int gm = gm0 + r;
                    const int bb = gm >> 11, tt = gm & 2047;
                    outp[((size_t)(bb * 16 + hh) * 2048 + tt) * 64 + dd] =
                        f2bf((acc[mt][nt][r] + bvv) * qscale);
                }
            } else {
                const int bb = gm0 >> 11, t0 = gm0 & 2047;
                // permuted key column: p0 = (t0&~31) | quad_k*8 | mt_k*4
                const int c5 = t0 & 31;
                const int p0 = (t0 & ~31) | (((c5 & 15) >> 2) << 3) | ((c5 >> 4) << 2);
                ushort4 pk;
                pk.x = f2bf(acc[mt][nt][0] + bvv);
                pk.y = f2bf(acc[mt][nt][1] + bvv);
                pk.z = f2bf(acc[mt][nt][2] + bvv);
                pk.w = f2bf(acc[mt][nt][3] + bvv);
                *(ushort4*)(outp + ((size_t)(bb * 16 + hh) * 64 + dd) * 2048 + p0) = pk;
            }
        }
}

// ---------------------------------------------------------------------------
// Wo GEMM R22. 128x64 tile, flat grid 512, XCD swizzle.
// 16 pair-periods; 3 pair-buffers (6 sub-bufs: X 6x8KB + W 6x4KB = 72KB,
// 2 blocks/CU grid-limited). Depth-2 pair prefetch with counted vmcnt(6)
// + raw s_barrier -- pair p+1's 6 loads stay in flight across the barrier.
// ---------------------------------------------------------------------------
__global__ __launch_bounds__(256)
void gemm_out(const unsigned short* __restrict__ X, const unsigned short* __restrict__ W,
              const float* __restrict__ bias, float* __restrict__ outp)
{
    __shared__ unsigned short Xs[6 * 4096], Ws[6 * 2048];   // 48KB + 24KB
    const int tid = threadIdx.x;
    const int w = tid >> 6, ln = tid & 63;
    const int quad = ln >> 4, L = ln & 15;

    const int bid = blockIdx.x;
    const int xcd = bid & 7, j = bid >> 3;
    const int m0 = (xcd * 4 + (j >> 4)) * 128;
    const int n0 = (j & 15) * 64;

    // staging geometry (loop-invariant): 3 gl16 per wave per 32-K sub-tile
    const int cix0 = ln, cix1 = 64 + ln;
    const int rowx0 = w * 32 + (cix0 >> 2), rowx1 = w * 32 + (cix1 >> 2);
    const int gcx0 = (cix0 & 3) ^ ((rowx0 >> 1) & 3);
    const int gcx1 = (cix1 & 3) ^ ((rowx1 >> 1) & 3);
    const int roww = w * 16 + (ln >> 2);
    const int gcw = (ln & 3) ^ ((roww >> 1) & 3);
    const size_t gxx0 = (size_t)(m0 + rowx0) * 1024 + gcx0 * 8;
    const size_t gxx1 = (size_t)(m0 + rowx1) * 1024 + gcx1 * 8;
    const size_t gww  = (size_t)(n0 + roww) * 1024 + gcw * 8;

    f32x4 acc[2][4];
#pragma unroll
    for (int i = 0; i < 2; ++i)
#pragma unroll
        for (int jj = 0; jj < 4; ++jj) { f32x4 z = {0.f,0.f,0.f,0.f}; acc[i][jj] = z; }

    // kt_ = 32-K sub-tile index (0..31); sb_ = sub-buffer slot (0..5)
#define OSTAGE(kt_, sb_)                                                       \
    do {                                                                       \
        gl16(X + gxx0 + (kt_) * 32, (char*)Xs + (sb_) * 8192 + w * 2048);      \
        gl16(X + gxx1 + (kt_) * 32, (char*)Xs + (sb_) * 8192 + w * 2048 + 1024); \
        gl16(W + gww  + (kt_) * 32, (char*)Ws + (sb_) * 4096 + w * 1024);      \
    } while (0)

#define OCOMP(sb_)                                                             \
    do {                                                                       \
        const unsigned short* Xc = Xs + (sb_) * 4096;                          \
        const unsigned short* Wc = Ws + (sb_) * 2048;                          \
        bf16x8 ah[2], bh[4];                                                   \
        _Pragma("unroll")                                                      \
        for (int mt = 0; mt < 2; ++mt) {                                       \
            const int row = w * 32 + mt * 16 + L;                              \
            ah[mt] = *(const bf16x8*)(Xc + row * 32 +                          \
                                      ((quad ^ ((row >> 1) & 3)) * 8));        \
        }                                                                      \
        _Pragma("unroll")                                                      \
        for (int nt = 0; nt < 4; ++nt) {                                       \
            const int row = nt * 16 + L;                                       \
            bh[nt] = *(const bf16x8*)(Wc + row * 32 +                          \
                                      ((quad ^ ((row >> 1) & 3)) * 8));        \
        }                                                                      \
        _Pragma("unroll")                                                      \
        for (int mt = 0; mt < 2; ++mt)                                         \
            _Pragma("unroll")                                                  \
            for (int nt = 0; nt < 4; ++nt)                                     \
                acc[mt][nt] = mfma16(ah[mt], bh[nt], acc[mt][nt]);             \
    } while (0)

    OSTAGE(0, 0); OSTAGE(1, 1);     // pair 0
    OSTAGE(2, 2); OSTAGE(3, 3);     // pair 1

    for (int p = 0; p < 16; ++p) {
        // own pair's 6 loads done; pair p+1's 6 may stay in flight
        if (p < 15) {
            asm volatile("s_waitcnt vmcnt(6)" ::: "memory");
        } else {
            asm volatile("s_waitcnt vmcnt(0)" ::: "memory");
        }
        __builtin_amdgcn_s_barrier();
        asm volatile("" ::: "memory");
        const int sb = (2 * p) % 6;
        if (p < 14) {               // stage pair p+2 into slot computed at p-1
            const int st = (2 * p + 4) % 6;
            OSTAGE(2 * p + 4, st);
            OSTAGE(2 * p + 5, st + 1);
        }
        OCOMP(sb);
        OCOMP(sb + 1);
    }
#undef OSTAGE
#undef OCOMP

#pragma unroll
    for (int mt = 0; mt < 2; ++mt)
#pragma unroll
        for (int nt = 0; nt < 4; ++nt) {
            const int gm0 = m0 + w * 32 + mt * 16 + quad * 4;
            const int gn  = n0 + nt * 16 + L;
            const float bvv = bias[gn];
#pragma unroll
            for (int r = 0; r < 4; ++r)
                outp[(size_t)(gm0 + r) * 1024 + gn] = acc[mt][nt][r] + bvv;
        }
}

// ---------------------------------------------------------------------------
// Flash R18 (unchanged). Flat grid 512 (256 thr): xcd=bid&7, j=bid>>3,
// bh=xcd*4+(j&3), qt=j>>2 (q-tile 128). Wave (wq,wk) owns q-half wq (64
// rows) x key-half wk (32 keys of each 64-key sub-tile). S^T = K Q^T, O^T =
// V^T P^T, P in registers (slot k = quad*8 + mt*4 + r). TWO 64-key sub-
// tiles per barrier period (16 periods); K/V double-buffered at period
// granularity. V LDS key-permuted (producer) -> av = one ds_read_b128/frag.
// LDS 66KB -> 2 blocks/CU. Epilogue O-reduce through retired LDS.
// ---------------------------------------------------------------------------
__global__ __launch_bounds__(256, 2)
void flash(const unsigned short* __restrict__ Qh, const unsigned short* __restrict__ Kh,
           const unsigned short* __restrict__ Vt, unsigned short* __restrict__ A)
{
    __shared__ unsigned short SM[32768];         // 64KB: K [0,32KB), V [32,64KB)
    __shared__ float Lsc[2 * 4 * 64];            // 2KB cross-wave lacc scalars
    const int tid = threadIdx.x;
    const int w = tid >> 6, ln = tid & 63;
    const int quad = ln >> 4, L = ln & 15;
    const int wq = w & 1, wk = w >> 1;

    const int bid = blockIdx.x;
    const int xcd = bid & 7, j = bid >> 3;
    const int bh_i = xcd * 4 + (j & 3);
    const int qt = j >> 2;                       // 0..15, 128-row q tiles
    const int b = bh_i >> 4, h = bh_i & 15;

    const unsigned short* Qb = Qh + ((size_t)bh_i * 2048 + qt * 128 + wq * 64) * 64;
    const unsigned short* Kb = Kh + (size_t)bh_i * 2048 * 64;
    const unsigned short* Vb = Vt + (size_t)bh_i * 64 * 2048;

    // Q as B-operand: B[n=q=nt*16+L][k=d]
    bf16x8 bq[4][2];
#pragma unroll
    for (int nt = 0; nt < 4; ++nt)
#pragma unroll
        for (int kc = 0; kc < 2; ++kc)
            bq[nt][kc] = *(const bf16x8*)(Qb + (nt * 16 + L) * 64 + kc * 32 + quad * 8);

    const short one_bf = (short)0x3F80;
    bf16x8 bone = {one_bf, one_bf, one_bf, one_bf, one_bf, one_bf, one_bf, one_bf};

    f32x4 o[4][4];        // O^T partial: [mtd over d][nt over q]
    f32x4 lacc[4];
#pragma unroll
    for (int mtd = 0; mtd < 4; ++mtd)
#pragma unroll
        for (int nt = 0; nt < 4; ++nt) { f32x4 z = {0.f,0.f,0.f,0.f}; o[mtd][nt] = z; }
#pragma unroll
    for (int nt = 0; nt < 4; ++nt) { f32x4 z = {0.f,0.f,0.f,0.f}; lacc[nt] = z; }

    // staging: per 64-key sub-tile, seg = w*2+i over 8 segs of 1KB
    const int ci0 = (w * 2 + 0) * 64 + ln, ci1 = (w * 2 + 1) * 64 + ln;
    const int rr0 = ci0 >> 3, rr1 = ci1 >> 3;
    const int gc0 = (ci0 & 7) ^ (rr0 & 7), gc1 = (ci1 & 7) ^ (rr1 & 7);

    // one sub-tile (global tile index kt_, period-buffer b_, sub-slot s_)
#define STAGE1(kt_, b_, s_)                                                     \
    do {                                                                        \
        gl16(Kb + (size_t)((kt_) * 64 + rr0) * 64 + gc0 * 8,                    \
             (char*)SM + (b_) * 16384 + (s_) * 8192 + (w * 2 + 0) * 1024);      \
        gl16(Kb + (size_t)((kt_) * 64 + rr1) * 64 + gc1 * 8,                    \
             (char*)SM + (b_) * 16384 + (s_) * 8192 + (w * 2 + 1) * 1024);      \
        gl16(Vb + (size_t)rr0 * 2048 + (kt_) * 64 + gc0 * 8,                    \
             (char*)SM + 32768 + (b_) * 16384 + (s_) * 8192 + (w * 2 + 0) * 1024); \
        gl16(Vb + (size_t)rr1 * 2048 + (kt_) * 64 + gc1 * 8,                    \
             (char*)SM + 32768 + (b_) * 16384 + (s_) * 8192 + (w * 2 + 1) * 1024); \
    } while (0)

    // compute one 64-key sub-tile from (buffer b_, sub-slot s_)
#define SUBCOMP(b_, s_)                                                         \
    do {                                                                        \
        const unsigned short* Ksb = SM + (b_) * 8192 + (s_) * 4096;             \
        const unsigned short* Vsb = SM + 16384 + (b_) * 8192 + (s_) * 4096;     \
        bf16x8 ak[2][2];                                                        \
        _Pragma("unroll")                                                       \
        for (int mt = 0; mt < 2; ++mt)                                          \
            _Pragma("unroll")                                                   \
            for (int kc = 0; kc < 2; ++kc) {                                    \
                const int row = wk * 32 + mt * 16 + L;                          \
                ak[mt][kc] = *(const bf16x8*)(Ksb + row * 64 +                  \
                                              (((kc * 4 + quad) ^ (L & 7)) * 8)); \
            }                                                                   \
        f32x4 s[2][4];                                                          \
        _Pragma("unroll")                                                       \
        for (int mt = 0; mt < 2; ++mt)                                          \
            _Pragma("unroll")                                                   \
            for (int nt = 0; nt < 4; ++nt) {                                    \
                f32x4 z = {0.f, 0.f, 0.f, 0.f};                                 \
                z = mfma16(ak[mt][0], bq[nt][0], z);                            \
                z = mfma16(ak[mt][1], bq[nt][1], z);                            \
                s[mt][nt] = z;                                                  \
            }                                                                   \
        bf16x8 pbx[4];                                                          \
        _Pragma("unroll")                                                       \
        for (int nt = 0; nt < 4; ++nt) {                                        \
            u32x4 pd;                                                           \
            pd.x = pk2bf(__builtin_amdgcn_exp2f(s[0][nt][0]),                   \
                         __builtin_amdgcn_exp2f(s[0][nt][1]));                  \
            pd.y = pk2bf(__builtin_amdgcn_exp2f(s[0][nt][2]),                   \
                         __builtin_amdgcn_exp2f(s[0][nt][3]));                  \
            pd.z = pk2bf(__builtin_amdgcn_exp2f(s[1][nt][0]),                   \
                         __builtin_amdgcn_exp2f(s[1][nt][1]));                  \
            pd.w = pk2bf(__builtin_amdgcn_exp2f(s[1][nt][2]),                   \
                         __builtin_amdgcn_exp2f(s[1][nt][3]));                  \
            pbx[nt] = __builtin_bit_cast(bf16x8, pd);                           \
        }                                                                       \
        bf16x8 av[4];                                                           \
        _Pragma("unroll")                                                       \
        for (int mtd = 0; mtd < 4; ++mtd) {                                     \
            const int row = mtd * 16 + L;                                       \
            av[mtd] = *(const bf16x8*)(Vsb + row * 64 +                         \
                                       (((wk * 4 + quad) ^ (L & 7)) * 8));      \
        }                                                                       \
        _Pragma("unroll")                                                       \
        for (int mtd = 0; mtd < 4; ++mtd)                                       \
            _Pragma("unroll")                                                   \
            for (int nt = 0; nt < 4; ++nt)                                      \
                o[mtd][nt] = mfma16(av[mtd], pbx[nt], o[mtd][nt]);              \
        _Pragma("unroll")                                                       \
        for (int nt = 0; nt < 4; ++nt)                                          \
            lacc[nt] = mfma16(bone, pbx[nt], lacc[nt]);                         \
    } while (0)

    STAGE1(0, 0, 0);
    STAGE1(1, 0, 1);

    for (int p = 0; p < 16; ++p) {
        const int cur = p & 1;
        __syncthreads();                       // period p staged & visible
        if (p < 15) {                          // prefetch period p+1
            STAGE1(2 * p + 2, cur ^ 1, 0);
            STAGE1(2 * p + 3, cur ^ 1, 1);
        }
        SUBCOMP(cur, 0);
        SUBCOMP(cur, 1);
    }
#undef STAGE1
#undef SUBCOMP

    // cross-wave reduction over key-halves through retired LDS
    __syncthreads();
    float* Rb = (float*)SM;               // 8192 floats = 32 KB (of 64)
    if (wk == 1) {
#pragma unroll
        for (int mtd = 0; mtd < 4; ++mtd)
#pragma unroll
            for (int nt = 0; nt < 4; ++nt)
                *(f32x4*)(Rb + wq * 4096 + (mtd * 4 + nt) * 256 + ln * 4) = o[mtd][nt];
#pragma unroll
        for (int nt = 0; nt < 4; ++nt)
            Lsc[wq * 256 + nt * 64 + ln] = lacc[nt][0];
    }
    __syncthreads();
    if (wk == 0) {
#pragma unroll
        for (int mtd = 0; mtd < 4; ++mtd)
#pragma unroll
            for (int nt = 0; nt < 4; ++nt)
                o[mtd][nt] += *(const f32x4*)(Rb + wq * 4096 + (mtd * 4 + nt) * 256 + ln * 4);

        // epilogue: O^T/l -> bf16 into A [B*T, D]; lane q=nt*16+L, rows d.
#pragma unroll
        for (int nt = 0; nt < 4; ++nt) {
            const float lsum = lacc[nt][0] + Lsc[wq * 256 + nt * 64 + ln];
            const float inv = 1.0f / lsum;
            const int qrow = b * 2048 + qt * 128 + wq * 64 + nt * 16 + L;
#pragma unroll
            for (int mtd = 0; mtd < 4; ++mtd) {
                const int d0 = mtd * 16 + quad * 4;
                ushort4 pk;
                pk.x = f2bf(o[mtd][nt][0] * inv);
                pk.y = f2bf(o[mtd][nt][1] * inv);
                pk.z = f2bf(o[mtd][nt][2] * inv);
                pk.w = f2bf(o[mtd][nt][3] * inv);
                *(ushort4*)(A + (size_t)qrow * 1024 + h * 64 + d0) = pk;
            }
        }
    }
}

// ---------------------------------------------------------------------------
extern "C" void kernel_launch(void* const* d_in, const int* in_sizes, int n_in,
                              void* d_out, int out_size, void* d_ws, size_t ws_size,
                              hipStream_t stream) {
    const float* q  = (const float*)d_in[0];
    const float* k  = (const float*)d_in[1];
    const float* v  = (const float*)d_in[2];
    const float* Wq = (const float*)d_in[3];
    const float* bq = (const float*)d_in[4];
    const float* Wk = (const float*)d_in[5];
    const float* bk = (const float*)d_in[6];
    const float* Wv = (const float*)d_in[7];
    const float* bv = (const float*)d_in[8];
    const float* Wo = (const float*)d_in[9];
    const float* bo = (const float*)d_in[10];

    unsigned short* W = (unsigned short*)d_ws;
    unsigned short *Xall = W;                      // q,k,v bf16 [3*E22]
    unsigned short *Wcat = W + 3 * E22;            // [3072,1024] bf16
    unsigned short *Wob  = Wcat + 3 * E20;         // [1024,1024] bf16
    unsigned short *Qhp  = W + 4 * E22;            // [B,H,T,64] (pre-scaled)
    unsigned short *Khp  = W + 5 * E22;
    unsigned short *Vtp  = W + 6 * E22;            // [B,H,64,T] key-permuted
    unsigned short *A    = W;                      // reuse q_b (dead)

    split_all<<<8192, 256, 0, stream>>>(q, k, v, Wq, Wk, Wv, Wo, W);

    gemm_qkv<<<768, 256, 0, stream>>>(Xall, Wcat, bq, bk, bv, Qhp, Khp, Vtp);

    flash<<<512, 256, 0, stream>>>(Qhp, Khp, Vtp, A);

    gemm_out<<<512, 256, 0, stream>>>(A, Wob, bo, (float*)d_out);
}